// Round 1
// baseline (209.800 us; speedup 1.0000x reference)
//
#include <hip/hip_runtime.h>
#include <hip/hip_bf16.h>
#include <math.h>

#define RR 1024
#define BB 16
#define DD 1024
#define K_ACTIVE 20

// ---------------------------------------------------------------------------
// Kernel 1: per (r,b) pair compute dot(H[r,b,:], w) and sumsq(msg[r,b,:]),
// then adj[b,r] = s - theta[r] - refr[b,r] - 0.5*(0.9*fb[b,r] + 0.1*||msg||).
// One wave (64 lanes) per pair; 4 pairs per 256-thread block.
// ---------------------------------------------------------------------------
__global__ __launch_bounds__(256) void score_kernel(
    const float* __restrict__ H, const float* __restrict__ msg,
    const float* __restrict__ w, const float* __restrict__ theta,
    const float* __restrict__ refr, const float* __restrict__ fb,
    float* __restrict__ adj_out)
{
    const int wave = threadIdx.x >> 6;
    const int lane = threadIdx.x & 63;
    const int pair = blockIdx.x * 4 + wave;   // pair = r*BB + b (row-major [R,B])
    const int r = pair >> 4;
    const int b = pair & 15;

    const float4* H4 = (const float4*)(H + (size_t)pair * DD);
    const float4* M4 = (const float4*)(msg + (size_t)pair * DD);
    const float4* W4 = (const float4*)w;

    float dot = 0.f, ss = 0.f;
#pragma unroll
    for (int k = 0; k < 4; ++k) {
        const int i = lane + 64 * k;          // 256 float4 = 1024 floats
        const float4 h = H4[i];
        const float4 m = M4[i];
        const float4 ww = W4[i];
        dot += h.x * ww.x + h.y * ww.y + h.z * ww.z + h.w * ww.w;
        ss  += m.x * m.x + m.y * m.y + m.z * m.z + m.w * m.w;
    }
    // wave-64 reduction
#pragma unroll
    for (int off = 32; off > 0; off >>= 1) {
        dot += __shfl_down(dot, off);
        ss  += __shfl_down(ss, off);
    }
    if (lane == 0) {
        const float fb_mag = sqrtf(ss);
        const float fb_new = 0.9f * fb[b * RR + r] + 0.1f * fb_mag;
        const float a = dot - theta[r] - refr[b * RR + r] - 0.5f * fb_new;
        adj_out[b * RR + r] = a;
    }
}

// ---------------------------------------------------------------------------
// Kernel 2: greedy hex NMS, one block per batch. Equivalent to the reference
// scan over argsort(-adj): repeat K times { pick max over non-suppressed
// (tie -> lowest index, matching stable argsort); select it; suppress it and
// its 6 neighbors }.
// ---------------------------------------------------------------------------
__global__ __launch_bounds__(256) void nms_kernel(
    const float* __restrict__ adj, const int* __restrict__ nbrs,
    float* __restrict__ hard)
{
    __shared__ float val[RR];
    __shared__ unsigned char sel[RR];
    __shared__ float wv[4];
    __shared__ int wi[4];

    const int b = blockIdx.x;
    const int tid = threadIdx.x;
    const int lane = tid & 63;
    const int wave = tid >> 6;

#pragma unroll
    for (int j = 0; j < 4; ++j) {
        const int i = tid + 256 * j;
        val[i] = adj[b * RR + i];
        sel[i] = 0;
    }
    __syncthreads();

    for (int it = 0; it < K_ACTIVE; ++it) {
        float m = -INFINITY;
        int mi = RR;  // sentinel > any valid index
#pragma unroll
        for (int j = 0; j < 4; ++j) {
            const int i = tid + 256 * j;
            const float v = val[i];
            if (v > m || (v == m && i < mi)) { m = v; mi = i; }
        }
        // wave-64 argmax reduce (tie -> lower index)
#pragma unroll
        for (int off = 32; off > 0; off >>= 1) {
            const float ov = __shfl_down(m, off);
            const int   oi = __shfl_down(mi, off);
            if (ov > m || (ov == m && oi < mi)) { m = ov; mi = oi; }
        }
        if (lane == 0) { wv[wave] = m; wi[wave] = mi; }
        __syncthreads();
        if (tid == 0) {
            float bm = wv[0];
            int bi = wi[0];
#pragma unroll
            for (int q = 1; q < 4; ++q) {
                if (wv[q] > bm || (wv[q] == bm && wi[q] < bi)) { bm = wv[q]; bi = wi[q]; }
            }
            if (bm > -INFINITY) {
                sel[bi] = 1;
                val[bi] = -INFINITY;
#pragma unroll
                for (int j = 0; j < 6; ++j) val[nbrs[bi * 6 + j]] = -INFINITY;
            }
        }
        __syncthreads();
    }

#pragma unroll
    for (int j = 0; j < 4; ++j) {
        const int i = tid + 256 * j;
        hard[b * RR + i] = sel[i] ? 1.0f : 0.0f;
    }
}

// ---------------------------------------------------------------------------
// Kernel 3: Hs[r,b,:] = hard[b,r] ? H[r,b,:] : 0. One block per (r,b) pair,
// one float4 per thread. Gated-off rows write zeros without reading H
// (H*0 == ±0, absmax-identical), so only ~2% of H is re-read.
// ---------------------------------------------------------------------------
__global__ __launch_bounds__(256) void gate_kernel(
    const float* __restrict__ H, const float* __restrict__ hard,
    float* __restrict__ Hs)
{
    const int pair = blockIdx.x;      // pair = r*BB + b
    const int r = pair >> 4;
    const int b = pair & 15;
    const float g = hard[b * RR + r];

    float4* out4 = (float4*)(Hs + (size_t)pair * DD);
    if (g != 0.0f) {
        const float4* H4 = (const float4*)(H + (size_t)pair * DD);
        out4[threadIdx.x] = H4[threadIdx.x];
    } else {
        out4[threadIdx.x] = make_float4(0.f, 0.f, 0.f, 0.f);
    }
}

extern "C" void kernel_launch(void* const* d_in, const int* in_sizes, int n_in,
                              void* d_out, int out_size, void* d_ws, size_t ws_size,
                              hipStream_t stream) {
    const float* H     = (const float*)d_in[0];   // [R,B,D]
    const float* msg   = (const float*)d_in[1];   // [R,B,D]
    const float* w     = (const float*)d_in[2];   // [D]
    const float* theta = (const float*)d_in[3];   // [R]
    const float* refr  = (const float*)d_in[4];   // [B,R]
    const float* fb    = (const float*)d_in[5];   // [B,R]
    const int*   nbrs  = (const int*)d_in[6];     // [R,6]

    float* out  = (float*)d_out;
    float* Hs   = out;                                   // [R,B,D]
    float* hard = out + (size_t)RR * BB * DD;            // [B,R]
    float* adj  = hard + (size_t)BB * RR;                // [B,R]

    score_kernel<<<RR * BB / 4, 256, 0, stream>>>(H, msg, w, theta, refr, fb, adj);
    nms_kernel<<<BB, 256, 0, stream>>>(adj, nbrs, hard);
    gate_kernel<<<RR * BB, 256, 0, stream>>>(H, hard, Hs);
}